// Round 12
// baseline (307.031 us; speedup 1.0000x reference)
//
#include <hip/hip_runtime.h>
#include <hip/hip_bf16.h>

typedef float f32x4 __attribute__((ext_vector_type(4)));
typedef __bf16 bf16x8 __attribute__((ext_vector_type(8)));
typedef unsigned short ushort_t;
typedef ushort_t u16x8 __attribute__((ext_vector_type(8)));

// ---------------------------------------------------------------------------
// fp32 -> bf16 round-to-nearest-even
// ---------------------------------------------------------------------------
__device__ inline ushort_t f2bf_rne(float f) {
  unsigned u = __builtin_bit_cast(unsigned, f);
  unsigned r = (u + 0x7fffu + ((u >> 16) & 1u)) >> 16;
  return (ushort_t)r;
}

// ---------------------------------------------------------------------------
// Kernel 1: 2:4 prune (exact fp32 argsort-stable semantics) + cast to bf16.
// ---------------------------------------------------------------------------
__global__ void prune_cast_kernel(const float* __restrict__ x,
                                  ushort_t* __restrict__ xsp, long n8) {
  long i = (long)blockIdx.x * blockDim.x + threadIdx.x;
  if (i >= n8) return;
  const float4* p = reinterpret_cast<const float4*>(x);
  float4 g0 = p[2 * i];
  float4 g1 = p[2 * i + 1];
  float v[8] = {g0.x, g0.y, g0.z, g0.w, g1.x, g1.y, g1.z, g1.w};
  u16x8 o;
#pragma unroll
  for (int g = 0; g < 2; ++g) {
    float a[4];
#pragma unroll
    for (int j = 0; j < 4; ++j) a[j] = fabsf(v[g * 4 + j]);
#pragma unroll
    for (int j = 0; j < 4; ++j) {
      int rank = 0;
#pragma unroll
      for (int k = 0; k < 4; ++k) {
        if (k == j) continue;
        rank += (a[k] < a[j]) || (a[k] == a[j] && k < j);
      }
      o[g * 4 + j] = (rank >= 2) ? f2bf_rne(v[g * 4 + j]) : (ushort_t)0;
    }
  }
  reinterpret_cast<u16x8*>(xsp)[i] = o;
}

// ---------------------------------------------------------------------------
// Kernel 2: fp32 -> bf16 cast of the weight matrix.
// ---------------------------------------------------------------------------
__global__ void cast_bf16_kernel(const float* __restrict__ w,
                                 ushort_t* __restrict__ wb, long n8) {
  long i = (long)blockIdx.x * blockDim.x + threadIdx.x;
  if (i >= n8) return;
  const float4* p = reinterpret_cast<const float4*>(w);
  float4 g0 = p[2 * i];
  float4 g1 = p[2 * i + 1];
  u16x8 o;
  o[0] = f2bf_rne(g0.x); o[1] = f2bf_rne(g0.y);
  o[2] = f2bf_rne(g0.z); o[3] = f2bf_rne(g0.w);
  o[4] = f2bf_rne(g1.x); o[5] = f2bf_rne(g1.y);
  o[6] = f2bf_rne(g1.z); o[7] = f2bf_rne(g1.w);
  reinterpret_cast<u16x8*>(wb)[i] = o;
}

// ---------------------------------------------------------------------------
// Kernel 3: 256x256 bf16 GEMM, ONE barrier per K-tile, counted vmcnt(4).
// C[m][n] = sum_k A[m][k]*B[n][k].  8 waves (2Mx4N), BK=64, 16x16x32 MFMA.
// LDS 160 KiB: A double-buffered (2 x 32 KiB), B TRIPLE-buffered (3 x 32 KiB).
// 3-bit XOR swizzle (physical 16B-chunk = logical ^ (row&7)) -> 0 conflicts.
//
// Round-12 schedule: per tile t (A parity PAR = t&1, B read slot br = t%3,
// B write slot bw = (t+2)%3):
//   - stage A(t+1) -> A parity PAR^1   (slots dead since tile t-1's barrier)
//   - stage B(t+2) -> B slot bw        (slot last read at t-1 -> dead)
//   - 24 ds_reads + 64 MFMAs in ONE barrier-free region
//   - vmcnt(4): retires A(t+1) and B(t+1); keeps B(t+2) in flight
//   - s_barrier  (single sync point per tile)
// Tail: stage targets clamp to NT-1; dup/junk writes land in dead slots
// (verified case-by-case); last two tiles drain with vmcnt(0).
// ---------------------------------------------------------------------------
#define BARM()                              \
  asm volatile("" ::: "memory");            \
  __builtin_amdgcn_s_barrier();             \
  asm volatile("" ::: "memory");
#define WAIT_VM4() asm volatile("s_waitcnt vmcnt(4)" ::: "memory")
#define WAIT_VM0() asm volatile("s_waitcnt vmcnt(0)" ::: "memory")

#define STAGE_A(t1, h, par)                                                    \
  {                                                                            \
    const ushort_t* g0 =                                                       \
        A + (a_row0 + (h) * 128 + srow) * (long)Kd + (t1) * 64 + scol;         \
    const ushort_t* g1 =                                                       \
        A + (a_row0 + (h) * 128 + srow + 8) * (long)Kd + (t1) * 64 + scol;     \
    ushort_t* l0 = &ldsA[((par) * 2 + (h)) * 8192 + w * 1024];                 \
    __builtin_amdgcn_global_load_lds(                                          \
        (const __attribute__((address_space(1))) void*)g0,                     \
        (__attribute__((address_space(3))) void*)l0, 16, 0, 0);                \
    __builtin_amdgcn_global_load_lds(                                          \
        (const __attribute__((address_space(1))) void*)g1,                     \
        (__attribute__((address_space(3))) void*)(l0 + 512), 16, 0, 0);        \
  }

// slot is a runtime int 0..2
#define STAGE_B(t1, h, slot)                                                   \
  {                                                                            \
    const ushort_t* g0 =                                                       \
        B + (b_row0 + (h) * 128 + srow) * (long)Kd + (t1) * 64 + scol;         \
    const ushort_t* g1 =                                                       \
        B + (b_row0 + (h) * 128 + srow + 8) * (long)Kd + (t1) * 64 + scol;     \
    ushort_t* l0 = &ldsB[((slot) * 2 + (h)) * 8192 + w * 1024];                \
    __builtin_amdgcn_global_load_lds(                                          \
        (const __attribute__((address_space(1))) void*)g0,                     \
        (__attribute__((address_space(3))) void*)l0, 16, 0, 0);                \
    __builtin_amdgcn_global_load_lds(                                          \
        (const __attribute__((address_space(1))) void*)g1,                     \
        (__attribute__((address_space(3))) void*)(l0 + 512), 16, 0, 0);        \
  }

#define LDA_FRAG(dst, par, mi, s)                                              \
  dst = *reinterpret_cast<const bf16x8*>(                                      \
      reinterpret_cast<const char*>(ldsA) + ((par) * 2 + wr) * 16384 +         \
      (mi) * 2048 + ((s) ? roff1 : roff0));

// br is a runtime slot int 0..2
#define LDB_FRAG(dst, br, ni, s)                                               \
  dst = *reinterpret_cast<const bf16x8*>(                                      \
      reinterpret_cast<const char*>(ldsB) + (br) * 32768 +                     \
      (wc >> 1) * 16384 + (wc & 1) * 8192 + (ni) * 2048 +                      \
      ((s) ? roff1 : roff0));

// s-outer: distance 8 between dependent updates of the same acc register.
#define MFMA_Q(MH, NH)                                                         \
  __builtin_amdgcn_s_setprio(1);                                               \
  _Pragma("unroll") for (int s = 0; s < 2; ++s)                                \
  _Pragma("unroll") for (int mi = 0; mi < 4; ++mi)                             \
  _Pragma("unroll") for (int ni = 0; ni < 2; ++ni)                             \
      acc[(MH) * 4 + mi][(NH) * 2 + ni] =                                      \
          __builtin_amdgcn_mfma_f32_16x16x32_bf16(                             \
              af[mi][s], bfr[(NH) * 2 + ni][s],                                \
              acc[(MH) * 4 + mi][(NH) * 2 + ni], 0, 0, 0);                     \
  __builtin_amdgcn_s_setprio(0);

#define KTILE(t, PAR)                                                          \
  {                                                                            \
    const int tA = ((t) + 1 < NT) ? (t) + 1 : NT - 1;                          \
    const int tB = ((t) + 2 < NT) ? (t) + 2 : NT - 1;                          \
    /* stages first: max flight.  A -> opposite parity, B -> slot bw */        \
    STAGE_A(tA, 0, (PAR) ^ 1)                                                  \
    STAGE_A(tA, 1, (PAR) ^ 1)                                                  \
    STAGE_B(tB, 0, bw)                                                         \
    STAGE_B(tB, 1, bw)                                                         \
    /* one region: 24 ds_reads + 64 MFMAs, no interior sync */                 \
    _Pragma("unroll") for (int mi = 0; mi < 4; ++mi)                           \
    _Pragma("unroll") for (int s = 0; s < 2; ++s)                              \
        LDA_FRAG(af[mi][s], PAR, mi, s)                                        \
    _Pragma("unroll") for (int ni = 0; ni < 4; ++ni)                           \
    _Pragma("unroll") for (int s = 0; s < 2; ++s)                              \
        LDB_FRAG(bfr[ni][s], br, ni, s)                                        \
    MFMA_Q(0, 0)                                                               \
    MFMA_Q(0, 1)                                                               \
    _Pragma("unroll") for (int mi = 0; mi < 4; ++mi)                           \
    _Pragma("unroll") for (int s = 0; s < 2; ++s)                              \
        LDA_FRAG(af[mi][s], PAR, 4 + mi, s)                                    \
    MFMA_Q(1, 1)                                                               \
    MFMA_Q(1, 0)                                                               \
    if ((t) + 2 < NT) { WAIT_VM4(); } else { WAIT_VM0(); }                     \
    BARM()                                                                     \
    br = (br == 2) ? 0 : br + 1;                                               \
    bw = (bw == 2) ? 0 : bw + 1;                                               \
  }

__global__ __launch_bounds__(512, 1) void gemm256_kernel(
    const ushort_t* __restrict__ A,  // [M][K] bf16 (pruned x)
    const ushort_t* __restrict__ B,  // [N][K] bf16 (weight)
    float* __restrict__ C,           // [M][N] fp32
    int M, int N, int Kd) {
  __shared__ ushort_t ldsA[4 * 8192];  // 2 parity x 32 KiB = 64 KiB
  __shared__ ushort_t ldsB[6 * 8192];  // 3 slots  x 32 KiB = 96 KiB

  const int tid = threadIdx.x;
  const int lane = tid & 63;
  const int w = tid >> 6;   // wave 0..7
  const int wr = w >> 2;    // 0..1 -> 128-row half
  const int wc = w & 3;     // 0..3 -> 64-col slab

  // XCD-bijective grid swizzle (gridDim.x % 8 == 0)
  const int b = blockIdx.x;
  const int wg = (b & 7) * (gridDim.x >> 3) + (b >> 3);
  const int nbn = N / 256;
  const int bm = wg / nbn, bn = wg % nbn;
  const long a_row0 = (long)bm * 256;
  const long b_row0 = (long)bn * 256;
  const int NT = Kd / 64;

  // staging: instr i of wave w, lane l writes LINEAR physical (row
  // 16w+8i+(l>>3), chunk l&7); swizzle physical(r,c) <- logical(r, c^(r&7))
  // -> global SOURCE chunk = (l&7) ^ ((l>>3)&7)  (same for both instrs).
  const int srow = w * 16 + (lane >> 3);
  const int scol = (((lane & 7) ^ ((lane >> 3) & 7)) << 3);  // ushort units

  // fragment read: logical (row rl, chunk q|s<<2) -> physical chunk
  // (q|s<<2) ^ (rl&7); s folded inside the XOR -> two precomputed offsets.
  const int rl = lane & 15;
  const int q = lane >> 4;
  const int roff0 = rl * 128 + (((q) ^ (rl & 7)) << 4);
  const int roff1 = rl * 128 + (((q | 4) ^ (rl & 7)) << 4);

  f32x4 acc[8][4];
#pragma unroll
  for (int i = 0; i < 8; ++i)
#pragma unroll
    for (int j = 0; j < 4; ++j) acc[i][j] = f32x4{0.f, 0.f, 0.f, 0.f};

  bf16x8 af[4][2];   // A fragments (mh0 then mh1; compiler renames)
  bf16x8 bfr[4][2];  // all 4 n fragments (persistent across the tile)

  int br = 0;  // B read slot  = t % 3
  int bw = 2;  // B write slot = (t+2) % 3

  // ---- prologue: A(0)->par0, B(0)->slot0, B(1)->slot1; vmcnt(4) keeps
  // B(1) in flight (retires A(0), B(0)); barrier ----
  STAGE_A(0, 0, 0)
  STAGE_A(0, 1, 0)
  STAGE_B(0, 0, 0)
  STAGE_B(0, 1, 0)
  STAGE_B(1, 0, 1)
  STAGE_B(1, 1, 1)
  WAIT_VM4();
  BARM()

  for (int t = 0; t < NT; t += 2) {
    KTILE(t, 0)
    KTILE(t + 1, 1)
  }

  // ---- epilogue: C/D layout col=lane&15, row=(lane>>4)*4+r ----
  const int orow = (lane >> 4) * 4;
  const int ocol = lane & 15;
#pragma unroll
  for (int mi = 0; mi < 8; ++mi)
#pragma unroll
    for (int ni = 0; ni < 4; ++ni) {
      const long r0 = a_row0 + wr * 128 + mi * 16 + orow;
      const long c0 = b_row0 + wc * 64 + ni * 16 + ocol;
#pragma unroll
      for (int r = 0; r < 4; ++r) C[(r0 + r) * N + c0] = acc[mi][ni][r];
    }
}

// ---------------------------------------------------------------------------
// Launch
// ---------------------------------------------------------------------------
extern "C" void kernel_launch(void* const* d_in, const int* in_sizes, int n_in,
                              void* d_out, int out_size, void* d_ws,
                              size_t ws_size, hipStream_t stream) {
  const float* x = (const float*)d_in[0];
  const float* w = (const float*)d_in[1];
  float* out = (float*)d_out;

  const int K = 4096;
  const long M = (long)in_sizes[0] / K;  // 8192
  const int N = in_sizes[1] / K;         // 4096

  ushort_t* xsp = (ushort_t*)d_ws;      // [M][K] bf16
  ushort_t* wb = xsp + (long)M * K;     // [N][K] bf16

  const long n8x = M * K / 8;
  prune_cast_kernel<<<(int)((n8x + 255) / 256), 256, 0, stream>>>(x, xsp, n8x);

  const long n8w = (long)N * K / 8;
  cast_bf16_kernel<<<(int)((n8w + 255) / 256), 256, 0, stream>>>(w, wb, n8w);

  const int nwg = (int)(M / 256) * (N / 256);  // 512, divisible by 8
  gemm256_kernel<<<nwg, 512, 0, stream>>>(xsp, wb, out, (int)M, N, K);
}

// Round 13
// 276.787 us; speedup vs baseline: 1.1093x; 1.1093x over previous
//
#include <hip/hip_runtime.h>
#include <hip/hip_bf16.h>

typedef float f32x4 __attribute__((ext_vector_type(4)));
typedef __bf16 bf16x8 __attribute__((ext_vector_type(8)));
typedef unsigned short ushort_t;
typedef ushort_t u16x8 __attribute__((ext_vector_type(8)));

// ---------------------------------------------------------------------------
// fp32 -> bf16 round-to-nearest-even
// ---------------------------------------------------------------------------
__device__ inline ushort_t f2bf_rne(float f) {
  unsigned u = __builtin_bit_cast(unsigned, f);
  unsigned r = (u + 0x7fffu + ((u >> 16) & 1u)) >> 16;
  return (ushort_t)r;
}

// ---------------------------------------------------------------------------
// Kernel 1: 2:4 prune (exact fp32 argsort-stable semantics) + cast to bf16.
// ---------------------------------------------------------------------------
__global__ void prune_cast_kernel(const float* __restrict__ x,
                                  ushort_t* __restrict__ xsp, long n8) {
  long i = (long)blockIdx.x * blockDim.x + threadIdx.x;
  if (i >= n8) return;
  const float4* p = reinterpret_cast<const float4*>(x);
  float4 g0 = p[2 * i];
  float4 g1 = p[2 * i + 1];
  float v[8] = {g0.x, g0.y, g0.z, g0.w, g1.x, g1.y, g1.z, g1.w};
  u16x8 o;
#pragma unroll
  for (int g = 0; g < 2; ++g) {
    float a[4];
#pragma unroll
    for (int j = 0; j < 4; ++j) a[j] = fabsf(v[g * 4 + j]);
#pragma unroll
    for (int j = 0; j < 4; ++j) {
      int rank = 0;
#pragma unroll
      for (int k = 0; k < 4; ++k) {
        if (k == j) continue;
        rank += (a[k] < a[j]) || (a[k] == a[j] && k < j);
      }
      o[g * 4 + j] = (rank >= 2) ? f2bf_rne(v[g * 4 + j]) : (ushort_t)0;
    }
  }
  reinterpret_cast<u16x8*>(xsp)[i] = o;
}

// ---------------------------------------------------------------------------
// Kernel 2: fp32 -> bf16 cast of the weight matrix.
// ---------------------------------------------------------------------------
__global__ void cast_bf16_kernel(const float* __restrict__ w,
                                 ushort_t* __restrict__ wb, long n8) {
  long i = (long)blockIdx.x * blockDim.x + threadIdx.x;
  if (i >= n8) return;
  const float4* p = reinterpret_cast<const float4*>(w);
  float4 g0 = p[2 * i];
  float4 g1 = p[2 * i + 1];
  u16x8 o;
  o[0] = f2bf_rne(g0.x); o[1] = f2bf_rne(g0.y);
  o[2] = f2bf_rne(g0.z); o[3] = f2bf_rne(g0.w);
  o[4] = f2bf_rne(g1.x); o[5] = f2bf_rne(g1.y);
  o[6] = f2bf_rne(g1.z); o[7] = f2bf_rne(g1.w);
  reinterpret_cast<u16x8*>(wb)[i] = o;
}

// ---------------------------------------------------------------------------
// Kernel 3: 256x256 bf16 GEMM, round-7 schedule with BALANCED regions.
// C[m][n] = sum_k A[m][k]*B[n][k].  8 waves (2Mx4N), BK=64, 128 KiB LDS
// double-buffered, 3-bit XOR swizzle (physical 16B-chunk = logical ^ (row&7))
// -> 0 bank conflicts.
//
// Round-13: same two sync points as round 7, but the mid-barrier moves to
// right after Q(0,1) (all four B fragments are consumed by then, which is
// exactly the mid-BAR's requirement: B reads delivered before any wave's
// B(t+2) stage writes the same-parity B slots).  The A-mh1 ds_reads and
// Q(1,1) shift into region 2, so BOTH regions carry LDS work and MFMA work:
//   region 1: 16 ds_reads + A(t+1)->PAR^1 stage + 32 MFMA
//   region 2:  8 ds_reads + B(t+2)->PAR  stage + 32 MFMA
// (round 7's region 2 had zero LDS work -> LDS pipe idled ~700 cyc/tile).
// Tile-end counted vmcnt(4): retires B(t+1)+A(t+1), keeps B(t+2) in flight;
// tail drains with vmcnt(0).  One setprio bracket per MFMA region.
// ---------------------------------------------------------------------------
#define BARM()                              \
  asm volatile("" ::: "memory");            \
  __builtin_amdgcn_s_barrier();             \
  asm volatile("" ::: "memory");
#define WAIT_VM4() asm volatile("s_waitcnt vmcnt(4)" ::: "memory")
#define WAIT_VM0() asm volatile("s_waitcnt vmcnt(0)" ::: "memory")

#define STAGE_A(t1, h, par)                                                    \
  {                                                                            \
    const ushort_t* g0 =                                                       \
        A + (a_row0 + (h) * 128 + srow) * (long)Kd + (t1) * 64 + scol;         \
    const ushort_t* g1 =                                                       \
        A + (a_row0 + (h) * 128 + srow + 8) * (long)Kd + (t1) * 64 + scol;     \
    ushort_t* l0 = &ldsA[((par) * 2 + (h)) * 8192 + w * 1024];                 \
    __builtin_amdgcn_global_load_lds(                                          \
        (const __attribute__((address_space(1))) void*)g0,                     \
        (__attribute__((address_space(3))) void*)l0, 16, 0, 0);                \
    __builtin_amdgcn_global_load_lds(                                          \
        (const __attribute__((address_space(1))) void*)g1,                     \
        (__attribute__((address_space(3))) void*)(l0 + 512), 16, 0, 0);        \
  }

#define STAGE_B(t1, h, par)                                                    \
  {                                                                            \
    const ushort_t* g0 =                                                       \
        B + (b_row0 + (h) * 128 + srow) * (long)Kd + (t1) * 64 + scol;         \
    const ushort_t* g1 =                                                       \
        B + (b_row0 + (h) * 128 + srow + 8) * (long)Kd + (t1) * 64 + scol;     \
    ushort_t* l0 = &ldsB[((par) * 2 + (h)) * 8192 + w * 1024];                 \
    __builtin_amdgcn_global_load_lds(                                          \
        (const __attribute__((address_space(1))) void*)g0,                     \
        (__attribute__((address_space(3))) void*)l0, 16, 0, 0);                \
    __builtin_amdgcn_global_load_lds(                                          \
        (const __attribute__((address_space(1))) void*)g1,                     \
        (__attribute__((address_space(3))) void*)(l0 + 512), 16, 0, 0);        \
  }

#define LDA_FRAG(dst, par, mi, s)                                              \
  dst = *reinterpret_cast<const bf16x8*>(                                      \
      reinterpret_cast<const char*>(ldsA) + ((par) * 2 + wr) * 16384 +         \
      (mi) * 2048 + ((s) ? roff1 : roff0));

#define LDB_FRAG(dst, par, ni, s)                                              \
  dst = *reinterpret_cast<const bf16x8*>(                                      \
      reinterpret_cast<const char*>(ldsB) + ((par) * 2 + (wc >> 1)) * 16384 +  \
      (wc & 1) * 8192 + (ni) * 2048 + ((s) ? roff1 : roff0));

// s-outer: distance 8 between dependent updates of the same acc register.
// No setprio here -- bracketed once per region.
#define MFMA_Q(MH, NH)                                                         \
  _Pragma("unroll") for (int s = 0; s < 2; ++s)                                \
  _Pragma("unroll") for (int mi = 0; mi < 4; ++mi)                             \
  _Pragma("unroll") for (int ni = 0; ni < 2; ++ni)                             \
      acc[(MH) * 4 + mi][(NH) * 2 + ni] =                                      \
          __builtin_amdgcn_mfma_f32_16x16x32_bf16(                             \
              af[mi][s], bfr[(NH) * 2 + ni][s],                                \
              acc[(MH) * 4 + mi][(NH) * 2 + ni], 0, 0, 0);

#define KTILE(t, PAR)                                                          \
  {                                                                            \
    const int tA = ((t) + 1 < NT) ? (t) + 1 : NT - 1;                          \
    const int tB = ((t) + 2 < NT) ? (t) + 2 : NT - 1;                          \
    /* region 1: A-mh0 + B reads ; stage A(t+1,op) ; 32 MFMA */                \
    _Pragma("unroll") for (int mi = 0; mi < 4; ++mi)                           \
    _Pragma("unroll") for (int s = 0; s < 2; ++s)                              \
        LDA_FRAG(af[mi][s], PAR, mi, s)                                        \
    _Pragma("unroll") for (int ni = 0; ni < 4; ++ni)                           \
    _Pragma("unroll") for (int s = 0; s < 2; ++s)                              \
        LDB_FRAG(bfr[ni][s], PAR, ni, s)                                       \
    STAGE_A(tA, 0, (PAR) ^ 1)                                                  \
    STAGE_A(tA, 1, (PAR) ^ 1)                                                  \
    __builtin_amdgcn_s_setprio(1);                                             \
    MFMA_Q(0, 0)                                                               \
    MFMA_Q(0, 1)                                                               \
    __builtin_amdgcn_s_setprio(0);                                             \
    /* all four B fragments consumed on every wave -> B slots restageable */   \
    BARM()                                                                     \
    /* region 2: A-mh1 reads ; stage B(t+2, same par) ; 32 MFMA */             \
    STAGE_B(tB, 0, PAR)                                                        \
    STAGE_B(tB, 1, PAR)                                                        \
    _Pragma("unroll") for (int mi = 0; mi < 4; ++mi)                           \
    _Pragma("unroll") for (int s = 0; s < 2; ++s)                              \
        LDA_FRAG(af[mi][s], PAR, 4 + mi, s)                                    \
    __builtin_amdgcn_s_setprio(1);                                             \
    MFMA_Q(1, 1)                                                               \
    MFMA_Q(1, 0)                                                               \
    __builtin_amdgcn_s_setprio(0);                                             \
    if ((t) + 2 < NT) { WAIT_VM4(); } else { WAIT_VM0(); }                     \
    BARM()                                                                     \
  }

__global__ __launch_bounds__(512, 1) void gemm256_kernel(
    const ushort_t* __restrict__ A,  // [M][K] bf16 (pruned x)
    const ushort_t* __restrict__ B,  // [N][K] bf16 (weight)
    float* __restrict__ C,           // [M][N] fp32
    int M, int N, int Kd) {
  __shared__ ushort_t ldsA[4 * 8192];  // 4 slots x 16 KiB (par,half)
  __shared__ ushort_t ldsB[4 * 8192];

  const int tid = threadIdx.x;
  const int lane = tid & 63;
  const int w = tid >> 6;   // wave 0..7
  const int wr = w >> 2;    // 0..1 -> 128-row half
  const int wc = w & 3;     // 0..3 -> 64-col slab

  // XCD-bijective grid swizzle (gridDim.x % 8 == 0)
  const int b = blockIdx.x;
  const int wg = (b & 7) * (gridDim.x >> 3) + (b >> 3);
  const int nbn = N / 256;
  const int bm = wg / nbn, bn = wg % nbn;
  const long a_row0 = (long)bm * 256;
  const long b_row0 = (long)bn * 256;
  const int NT = Kd / 64;

  // staging: instr i of wave w, lane l writes LINEAR physical (row
  // 16w+8i+(l>>3), chunk l&7); swizzle physical(r,c) <- logical(r, c^(r&7))
  // -> global SOURCE chunk = (l&7) ^ ((l>>3)&7)  (same for both instrs).
  const int srow = w * 16 + (lane >> 3);
  const int scol = (((lane & 7) ^ ((lane >> 3) & 7)) << 3);  // ushort units

  // fragment read: logical (row rl, chunk q|s<<2) -> physical chunk
  // (q|s<<2) ^ (rl&7); s folded inside the XOR -> two precomputed offsets.
  const int rl = lane & 15;
  const int q = lane >> 4;
  const int roff0 = rl * 128 + (((q) ^ (rl & 7)) << 4);
  const int roff1 = rl * 128 + (((q | 4) ^ (rl & 7)) << 4);

  f32x4 acc[8][4];
#pragma unroll
  for (int i = 0; i < 8; ++i)
#pragma unroll
    for (int j = 0; j < 4; ++j) acc[i][j] = f32x4{0.f, 0.f, 0.f, 0.f};

  bf16x8 af[4][2];   // A fragments (mh0 in region 1, mh1 in region 2)
  bf16x8 bfr[4][2];  // all 4 n fragments (consumed in region 1)

  // ---- prologue: stage tile 0 (par0) fully + B of tile 1 (par1); tile 1's
  // A halves get staged during tile 0 region 1. vmcnt(4): tile-0 landed. ----
  STAGE_A(0, 0, 0)
  STAGE_A(0, 1, 0)
  STAGE_B(0, 0, 0)
  STAGE_B(0, 1, 0)
  STAGE_B(1, 0, 1)
  STAGE_B(1, 1, 1)
  WAIT_VM4();
  BARM()

  for (int t = 0; t < NT; t += 2) {
    KTILE(t, 0)
    KTILE(t + 1, 1)
  }

  // ---- epilogue: C/D layout col=lane&15, row=(lane>>4)*4+r ----
  const int orow = (lane >> 4) * 4;
  const int ocol = lane & 15;
#pragma unroll
  for (int mi = 0; mi < 8; ++mi)
#pragma unroll
    for (int ni = 0; ni < 4; ++ni) {
      const long r0 = a_row0 + wr * 128 + mi * 16 + orow;
      const long c0 = b_row0 + wc * 64 + ni * 16 + ocol;
#pragma unroll
      for (int r = 0; r < 4; ++r) C[(r0 + r) * N + c0] = acc[mi][ni][r];
    }
}

// ---------------------------------------------------------------------------
// Launch
// ---------------------------------------------------------------------------
extern "C" void kernel_launch(void* const* d_in, const int* in_sizes, int n_in,
                              void* d_out, int out_size, void* d_ws,
                              size_t ws_size, hipStream_t stream) {
  const float* x = (const float*)d_in[0];
  const float* w = (const float*)d_in[1];
  float* out = (float*)d_out;

  const int K = 4096;
  const long M = (long)in_sizes[0] / K;  // 8192
  const int N = in_sizes[1] / K;         // 4096

  ushort_t* xsp = (ushort_t*)d_ws;      // [M][K] bf16
  ushort_t* wb = xsp + (long)M * K;     // [N][K] bf16

  const long n8x = M * K / 8;
  prune_cast_kernel<<<(int)((n8x + 255) / 256), 256, 0, stream>>>(x, xsp, n8x);

  const long n8w = (long)N * K / 8;
  cast_bf16_kernel<<<(int)((n8w + 255) / 256), 256, 0, stream>>>(w, wb, n8w);

  const int nwg = (int)(M / 256) * (N / 256);  // 512, divisible by 8
  gemm256_kernel<<<nwg, 512, 0, stream>>>(xsp, wb, out, (int)M, N, K);
}

// Round 14
// 264.864 us; speedup vs baseline: 1.1592x; 1.0450x over previous
//
#include <hip/hip_runtime.h>
#include <hip/hip_bf16.h>

typedef float f32x4 __attribute__((ext_vector_type(4)));
typedef __bf16 bf16x8 __attribute__((ext_vector_type(8)));
typedef unsigned short ushort_t;
typedef ushort_t u16x8 __attribute__((ext_vector_type(8)));

// ---------------------------------------------------------------------------
// fp32 -> bf16 round-to-nearest-even
// ---------------------------------------------------------------------------
__device__ inline ushort_t f2bf_rne(float f) {
  unsigned u = __builtin_bit_cast(unsigned, f);
  unsigned r = (u + 0x7fffu + ((u >> 16) & 1u)) >> 16;
  return (ushort_t)r;
}

// ---------------------------------------------------------------------------
// Kernel 1 (fused): 2:4 prune+cast of x  AND  plain cast of weight.
// Thread i < n8x: prune path on x -> xsp.  Else: cast path on w -> wb.
// Each thread handles 8 floats (two groups of 4 / 8 weights).
// ---------------------------------------------------------------------------
__global__ void prep_kernel(const float* __restrict__ x,
                            const float* __restrict__ w,
                            ushort_t* __restrict__ xsp,
                            ushort_t* __restrict__ wb, long n8x, long n8tot) {
  long i = (long)blockIdx.x * blockDim.x + threadIdx.x;
  if (i >= n8tot) return;
  if (i < n8x) {
    const float4* p = reinterpret_cast<const float4*>(x);
    float4 g0 = p[2 * i];
    float4 g1 = p[2 * i + 1];
    float v[8] = {g0.x, g0.y, g0.z, g0.w, g1.x, g1.y, g1.z, g1.w};
    u16x8 o;
#pragma unroll
    for (int g = 0; g < 2; ++g) {
      float a[4];
#pragma unroll
      for (int j = 0; j < 4; ++j) a[j] = fabsf(v[g * 4 + j]);
#pragma unroll
      for (int j = 0; j < 4; ++j) {
        int rank = 0;
#pragma unroll
        for (int k = 0; k < 4; ++k) {
          if (k == j) continue;
          // stable ascending sort rank: strictly-smaller, or equal-and-earlier
          rank += (a[k] < a[j]) || (a[k] == a[j] && k < j);
        }
        o[g * 4 + j] = (rank >= 2) ? f2bf_rne(v[g * 4 + j]) : (ushort_t)0;
      }
    }
    reinterpret_cast<u16x8*>(xsp)[i] = o;
  } else {
    long j = i - n8x;
    const float4* p = reinterpret_cast<const float4*>(w);
    float4 g0 = p[2 * j];
    float4 g1 = p[2 * j + 1];
    u16x8 o;
    o[0] = f2bf_rne(g0.x); o[1] = f2bf_rne(g0.y);
    o[2] = f2bf_rne(g0.z); o[3] = f2bf_rne(g0.w);
    o[4] = f2bf_rne(g1.x); o[5] = f2bf_rne(g1.y);
    o[6] = f2bf_rne(g1.z); o[7] = f2bf_rne(g1.w);
    reinterpret_cast<u16x8*>(wb)[j] = o;
  }
}

// ---------------------------------------------------------------------------
// Kernel 2: 256x256 bf16 GEMM, TWO barriers per K-tile (round-7 champion,
// verbatim).  C[m][n] = sum_k A[m][k]*B[n][k].  8 waves (2Mx4N), BK=64,
// 128 KiB LDS double-buffered, 3-bit XOR swizzle (physical 16B-chunk =
// logical ^ (row&7)) -> 0 bank conflicts.
//
// Per tile t (parity PAR):
//   region 1: A-mh0 + all-B ds_reads ; stage A(t+1)->PAR^1 ; Q(0,0) Q(0,1) ;
//             A-mh1 ds_reads ; Q(1,1)
//   mid-BAR   (all waves' B reads delivered -> B slots restageable)
//   region 2: stage B(t+2)->PAR ; Q(1,0)
//   tile-end: counted vmcnt(4) (retires A(t+1)+B(t+1), keeps B(t+2) in
//             flight), tail vmcnt(0) ; barrier
// ---------------------------------------------------------------------------
#define BARM()                              \
  asm volatile("" ::: "memory");            \
  __builtin_amdgcn_s_barrier();             \
  asm volatile("" ::: "memory");
#define WAIT_VM4() asm volatile("s_waitcnt vmcnt(4)" ::: "memory")
#define WAIT_VM0() asm volatile("s_waitcnt vmcnt(0)" ::: "memory")

#define STAGE_A(t1, h, par)                                                    \
  {                                                                            \
    const ushort_t* g0 =                                                       \
        A + (a_row0 + (h) * 128 + srow) * (long)Kd + (t1) * 64 + scol;         \
    const ushort_t* g1 =                                                       \
        A + (a_row0 + (h) * 128 + srow + 8) * (long)Kd + (t1) * 64 + scol;     \
    ushort_t* l0 = &ldsA[((par) * 2 + (h)) * 8192 + w * 1024];                 \
    __builtin_amdgcn_global_load_lds(                                          \
        (const __attribute__((address_space(1))) void*)g0,                     \
        (__attribute__((address_space(3))) void*)l0, 16, 0, 0);                \
    __builtin_amdgcn_global_load_lds(                                          \
        (const __attribute__((address_space(1))) void*)g1,                     \
        (__attribute__((address_space(3))) void*)(l0 + 512), 16, 0, 0);        \
  }

#define STAGE_B(t1, h, par)                                                    \
  {                                                                            \
    const ushort_t* g0 =                                                       \
        B + (b_row0 + (h) * 128 + srow) * (long)Kd + (t1) * 64 + scol;         \
    const ushort_t* g1 =                                                       \
        B + (b_row0 + (h) * 128 + srow + 8) * (long)Kd + (t1) * 64 + scol;     \
    ushort_t* l0 = &ldsB[((par) * 2 + (h)) * 8192 + w * 1024];                 \
    __builtin_amdgcn_global_load_lds(                                          \
        (const __attribute__((address_space(1))) void*)g0,                     \
        (__attribute__((address_space(3))) void*)l0, 16, 0, 0);                \
    __builtin_amdgcn_global_load_lds(                                          \
        (const __attribute__((address_space(1))) void*)g1,                     \
        (__attribute__((address_space(3))) void*)(l0 + 512), 16, 0, 0);        \
  }

#define LDA_FRAG(dst, par, mi, s)                                              \
  dst = *reinterpret_cast<const bf16x8*>(                                      \
      reinterpret_cast<const char*>(ldsA) + ((par) * 2 + wr) * 16384 +         \
      (mi) * 2048 + ((s) ? roff1 : roff0));

#define LDB_FRAG(dst, par, ni, s)                                              \
  dst = *reinterpret_cast<const bf16x8*>(                                      \
      reinterpret_cast<const char*>(ldsB) + ((par) * 2 + (wc >> 1)) * 16384 +  \
      (wc & 1) * 8192 + (ni) * 2048 + ((s) ? roff1 : roff0));

// s-outer: distance 8 between dependent updates of the same acc register.
#define MFMA_Q(MH, NH)                                                         \
  __builtin_amdgcn_s_setprio(1);                                               \
  _Pragma("unroll") for (int s = 0; s < 2; ++s)                                \
  _Pragma("unroll") for (int mi = 0; mi < 4; ++mi)                             \
  _Pragma("unroll") for (int ni = 0; ni < 2; ++ni)                             \
      acc[(MH) * 4 + mi][(NH) * 2 + ni] =                                      \
          __builtin_amdgcn_mfma_f32_16x16x32_bf16(                             \
              af[mi][s], bfr[(NH) * 2 + ni][s],                                \
              acc[(MH) * 4 + mi][(NH) * 2 + ni], 0, 0, 0);                     \
  __builtin_amdgcn_s_setprio(0);

#define KTILE(t, PAR)                                                          \
  {                                                                            \
    const int tA = ((t) + 1 < NT) ? (t) + 1 : NT - 1;                          \
    const int tB = ((t) + 2 < NT) ? (t) + 2 : NT - 1;                          \
    /* region 1: reads + A-stage + 48 MFMAs, one barrier-free region */        \
    _Pragma("unroll") for (int mi = 0; mi < 4; ++mi)                           \
    _Pragma("unroll") for (int s = 0; s < 2; ++s)                              \
        LDA_FRAG(af[mi][s], PAR, mi, s)                                        \
    _Pragma("unroll") for (int ni = 0; ni < 4; ++ni)                           \
    _Pragma("unroll") for (int s = 0; s < 2; ++s)                              \
        LDB_FRAG(bfr[ni][s], PAR, ni, s)                                       \
    STAGE_A(tA, 0, (PAR) ^ 1)                                                  \
    STAGE_A(tA, 1, (PAR) ^ 1)                                                  \
    MFMA_Q(0, 0)                                                               \
    MFMA_Q(0, 1)                                                               \
    _Pragma("unroll") for (int mi = 0; mi < 4; ++mi)                           \
    _Pragma("unroll") for (int s = 0; s < 2; ++s)                              \
        LDA_FRAG(af[mi][s], PAR, 4 + mi, s)                                    \
    MFMA_Q(1, 1)                                                               \
    /* all B reads delivered (consumed above) on every wave */                 \
    BARM()                                                                     \
    STAGE_B(tB, 0, PAR)                                                        \
    STAGE_B(tB, 1, PAR)                                                        \
    MFMA_Q(1, 0)                                                               \
    if ((t) + 2 < NT) { WAIT_VM4(); } else { WAIT_VM0(); }                     \
    BARM()                                                                     \
  }

__global__ __launch_bounds__(512, 1) void gemm256_kernel(
    const ushort_t* __restrict__ A,  // [M][K] bf16 (pruned x)
    const ushort_t* __restrict__ B,  // [N][K] bf16 (weight)
    float* __restrict__ C,           // [M][N] fp32
    int M, int N, int Kd) {
  __shared__ ushort_t ldsA[4 * 8192];  // 4 slots x 16 KiB (par,half)
  __shared__ ushort_t ldsB[4 * 8192];

  const int tid = threadIdx.x;
  const int lane = tid & 63;
  const int w = tid >> 6;   // wave 0..7
  const int wr = w >> 2;    // 0..1 -> 128-row half
  const int wc = w & 3;     // 0..3 -> 64-col slab

  // XCD-bijective grid swizzle (gridDim.x % 8 == 0)
  const int b = blockIdx.x;
  const int wg = (b & 7) * (gridDim.x >> 3) + (b >> 3);
  const int nbn = N / 256;
  const int bm = wg / nbn, bn = wg % nbn;
  const long a_row0 = (long)bm * 256;
  const long b_row0 = (long)bn * 256;
  const int NT = Kd / 64;

  // staging: instr i of wave w, lane l writes LINEAR physical (row
  // 16w+8i+(l>>3), chunk l&7); swizzle physical(r,c) <- logical(r, c^(r&7))
  // -> global SOURCE chunk = (l&7) ^ ((l>>3)&7)  (same for both instrs).
  const int srow = w * 16 + (lane >> 3);
  const int scol = (((lane & 7) ^ ((lane >> 3) & 7)) << 3);  // ushort units

  // fragment read: logical (row rl, chunk q|s<<2) -> physical chunk
  // (q|s<<2) ^ (rl&7); s folded inside the XOR -> two precomputed offsets.
  const int rl = lane & 15;
  const int q = lane >> 4;
  const int roff0 = rl * 128 + (((q) ^ (rl & 7)) << 4);
  const int roff1 = rl * 128 + (((q | 4) ^ (rl & 7)) << 4);

  f32x4 acc[8][4];
#pragma unroll
  for (int i = 0; i < 8; ++i)
#pragma unroll
    for (int j = 0; j < 4; ++j) acc[i][j] = f32x4{0.f, 0.f, 0.f, 0.f};

  bf16x8 af[4][2];   // A fragments (mh0 then mh1; compiler renames)
  bf16x8 bfr[4][2];  // all 4 n fragments (persistent across the tile)

  // ---- prologue: stage tile 0 (par0) fully + B of tile 1 (par1); tile 1's
  // A halves get staged during tile 0 region 1. vmcnt(4): tile-0 landed. ----
  STAGE_A(0, 0, 0)
  STAGE_A(0, 1, 0)
  STAGE_B(0, 0, 0)
  STAGE_B(0, 1, 0)
  STAGE_B(1, 0, 1)
  STAGE_B(1, 1, 1)
  WAIT_VM4();
  BARM()

  for (int t = 0; t < NT; t += 2) {
    KTILE(t, 0)
    KTILE(t + 1, 1)
  }
  WAIT_VM0();  // drain dangling clamped-tail prefetches before stores

  // ---- epilogue: C/D layout col=lane&15, row=(lane>>4)*4+r ----
  const int orow = (lane >> 4) * 4;
  const int ocol = lane & 15;
#pragma unroll
  for (int mi = 0; mi < 8; ++mi)
#pragma unroll
    for (int ni = 0; ni < 4; ++ni) {
      const long r0 = a_row0 + wr * 128 + mi * 16 + orow;
      const long c0 = b_row0 + wc * 64 + ni * 16 + ocol;
#pragma unroll
      for (int r = 0; r < 4; ++r) C[(r0 + r) * N + c0] = acc[mi][ni][r];
    }
}

// ---------------------------------------------------------------------------
// Launch
// ---------------------------------------------------------------------------
extern "C" void kernel_launch(void* const* d_in, const int* in_sizes, int n_in,
                              void* d_out, int out_size, void* d_ws,
                              size_t ws_size, hipStream_t stream) {
  const float* x = (const float*)d_in[0];
  const float* w = (const float*)d_in[1];
  float* out = (float*)d_out;

  const int K = 4096;
  const long M = (long)in_sizes[0] / K;  // 8192
  const int N = in_sizes[1] / K;         // 4096

  ushort_t* xsp = (ushort_t*)d_ws;      // [M][K] bf16
  ushort_t* wb = xsp + (long)M * K;     // [N][K] bf16

  const long n8x = M * K / 8;
  const long n8w = (long)N * K / 8;
  const long n8tot = n8x + n8w;
  prep_kernel<<<(int)((n8tot + 255) / 256), 256, 0, stream>>>(x, w, xsp, wb,
                                                              n8x, n8tot);

  const int nwg = (int)(M / 256) * (N / 256);  // 512, divisible by 8
  gemm256_kernel<<<nwg, 512, 0, stream>>>(xsp, wb, out, (int)M, N, K);
}